// Round 7
// baseline (309.432 us; speedup 1.0000x reference)
//
#include <hip/hip_runtime.h>
#include <hip/hip_bf16.h>

typedef __bf16 bf16;
typedef __bf16 bf16x2 __attribute__((ext_vector_type(2)));
typedef __bf16 bf16x4 __attribute__((ext_vector_type(4)));
typedef __bf16 bf16x8 __attribute__((ext_vector_type(8)));
typedef float f32x4 __attribute__((ext_vector_type(4)));

#define MFMA16(a, b, c) __builtin_amdgcn_mfma_f32_16x16x32_bf16((a), (b), (c), 0, 0, 0)

#if __has_builtin(__builtin_amdgcn_exp2f)
#define EXP2(x) __builtin_amdgcn_exp2f(x)
#else
#define EXP2(x) exp2f(x)
#endif

constexpr int EMBED = 1024;
constexpr int HEADS = 16;
constexpr int HD = 64;
constexpr int SEQ = 2048;
constexpr int LDSP = 72;   // padded LDS stride: 144 B rows (16B-aligned, 2-way banks = free)
constexpr int SXTP = 76;   // proj V-transpose stride
constexpr int WO_N = EMBED * EMBED;

// softmax scale 1/sqrt(1024) folded with log2(e); folded into Wq conversion
#define QSCALE 0.04508422082f

// pack two f32 -> one dword of 2 bf16 (compiler emits v_cvt_pk_bf16_f32)
static __device__ __forceinline__ unsigned pack2(float a, float b) {
    bf16x2 t;
    t[0] = (bf16)a;
    t[1] = (bf16)b;
    return __builtin_bit_cast(unsigned, t);
}
// gfx950 in-register half/row swaps (both operands read+write)
#define SWAP32(x, y) asm("v_permlane32_swap_b32 %0, %1" : "+v"(x), "+v"(y))
#define SWAP16(x, y) asm("v_permlane16_swap_b32 %0, %1" : "+v"(x), "+v"(y))

// ---------------- all weights fp32 -> bf16 (Q scale folded into Wq) --------
__global__ __launch_bounds__(256) void convert_weights(
    const float* __restrict__ Wo, const float* __restrict__ Wq,
    const float* __restrict__ Wk, const float* __restrict__ Wv,
    bf16* __restrict__ Wob, bf16* __restrict__ Wqb,
    bf16* __restrict__ Wkb, bf16* __restrict__ Wvb) {
    int gid = blockIdx.x * 256 + threadIdx.x;
    int base = gid * 8;
    const float* src;
    bf16* dst;
    float sc = 1.0f;
    int off;
    if (base < WO_N) {
        src = Wo; dst = Wob; off = base;
    } else {
        int j = base - WO_N;
        int w = j >> 12;
        off = j & 4095;
        src = (w == 0) ? Wq : (w == 1) ? Wk : Wv;
        dst = (w == 0) ? Wqb : (w == 1) ? Wkb : Wvb;
        if (w == 0) sc = QSCALE;
    }
    float4 a = *(const float4*)(src + off);
    float4 b = *(const float4*)(src + off + 4);
    bf16x8 o;
    o[0] = (bf16)(a.x * sc); o[1] = (bf16)(a.y * sc);
    o[2] = (bf16)(a.z * sc); o[3] = (bf16)(a.w * sc);
    o[4] = (bf16)(b.x * sc); o[5] = (bf16)(b.y * sc);
    o[6] = (bf16)(b.z * sc); o[7] = (bf16)(b.w * sc);
    *(bf16x8*)(dst + off) = o;
}

// ---------------- QKV per-head projections ----------------
// R5: all 3 tensors' A-row loads hoisted to kernel entry; split sT0/sT1
// transpose buffers (no cross-stage WAR barrier).
__global__ __launch_bounds__(256) void proj_kernel(
    const float* __restrict__ Vx, const float* __restrict__ Kx, const float* __restrict__ Qx,
    const bf16* __restrict__ Wqb, const bf16* __restrict__ Wkb, const bf16* __restrict__ Wvb,
    bf16* __restrict__ Vt, bf16* __restrict__ Kp, bf16* __restrict__ Qp) {
    __shared__ __align__(16) bf16 sT0[64 * LDSP];
    __shared__ __align__(16) bf16 sT1[64 * LDSP];
    __shared__ __align__(16) bf16 sXT[64 * SXTP];
    int t = threadIdx.x, lane = t & 63, wq = t >> 6;
    int m = lane & 15, q8 = lane >> 4;
    int rowbase = blockIdx.x * 64;
    int Arow = rowbase + wq * 16 + m;
    const float* Xs[3] = {Qx, Kx, Vx};
    const bf16* Ws[3] = {Wqb, Wkb, Wvb};
    f32x4 z = {0.f, 0.f, 0.f, 0.f};

    // hoisted A loads (T14 issue-early): all 3 ts stages' rows at once
    float4 ax[3][2][2];
#pragma unroll
    for (int ts = 0; ts < 3; ts++)
#pragma unroll
        for (int c = 0; c < 2; c++) {
            const float* s = Xs[ts] + (size_t)Arow * 64 + c * 32 + q8 * 8;
            ax[ts][c][0] = *(const float4*)s;
            ax[ts][c][1] = *(const float4*)(s + 4);
        }

#pragma unroll
    for (int ts = 0; ts < 3; ts++) {
        bf16x8 af[2];
#pragma unroll
        for (int c = 0; c < 2; c++) {
            float4 x0 = ax[ts][c][0];
            float4 x1 = ax[ts][c][1];
            bf16x8 a;
            a[0] = (bf16)x0.x; a[1] = (bf16)x0.y; a[2] = (bf16)x0.z; a[3] = (bf16)x0.w;
            a[4] = (bf16)x1.x; a[5] = (bf16)x1.y; a[6] = (bf16)x1.z; a[7] = (bf16)x1.w;
            af[c] = a;
        }
        bf16x8 bfr[4][2];
#pragma unroll
        for (int nt = 0; nt < 4; nt++)
#pragma unroll
            for (int c = 0; c < 2; c++)
                bfr[nt][c] = *(const bf16x8*)(Ws[ts] + (nt * 16 + m) * 64 + c * 32 + q8 * 8);
        f32x4 acc[4] = {z, z, z, z};
#pragma unroll
        for (int c = 0; c < 2; c++)
#pragma unroll
            for (int nt = 0; nt < 4; nt++)
                acc[nt] = MFMA16(af[c], bfr[nt][c], acc[nt]);

        if (ts < 2) {
            bf16* sT = (ts == 0) ? sT0 : sT1;   // static per unrolled ts
            for (int nt = 0; nt < 4; nt++)
                for (int jr = 0; jr < 4; jr++)
                    sT[(wq * 16 + q8 * 4 + jr) * LDSP + nt * 16 + m] = (bf16)acc[nt][jr];
            __syncthreads();
            // coalesced store: 4 threads per row, 16B chunks
            int r = t >> 2, c4 = t & 3;
            int R = rowbase + r;
            int h = R & 15, l = (R >> 4) & 2047, n = R >> 15;
            bf16* dst = ((ts == 0) ? Qp : Kp) + ((size_t)(n * HEADS + h) * SEQ + l) * HD + c4 * 16;
            bf16x8 v0 = *(const bf16x8*)&sT[r * LDSP + c4 * 16];
            bf16x8 v1 = *(const bf16x8*)&sT[r * LDSP + c4 * 16 + 8];
            *(bf16x8*)dst = v0;
            *(bf16x8*)(dst + 8) = v1;
        } else {
            // V: acc -> sXT[e][r], gather-transpose to Vt[n,h,d,l] (b64 stores)
            for (int nt = 0; nt < 4; nt++) {
                bf16x4 pv;
                pv[0] = (bf16)acc[nt][0]; pv[1] = (bf16)acc[nt][1];
                pv[2] = (bf16)acc[nt][2]; pv[3] = (bf16)acc[nt][3];
                *(bf16x4*)&sXT[(nt * 16 + m) * SXTP + wq * 16 + q8 * 4] = pv;
            }
            __syncthreads();
            int n = rowbase >> 15, l0 = (rowbase >> 4) & 2047;
            for (int i = t; i < 1024; i += 256) {
                int e = i & 63, hh = i >> 6;
                bf16x4 pv;
                pv[0] = sXT[e * SXTP + 0 * 16 + hh];
                pv[1] = sXT[e * SXTP + 1 * 16 + hh];
                pv[2] = sXT[e * SXTP + 2 * 16 + hh];
                pv[3] = sXT[e * SXTP + 3 * 16 + hh];
                *(bf16x4*)(Vt + ((size_t)(n * HEADS + hh) * HD + e) * SEQ + l0) = pv;
            }
        }
    }
}

// ---------------- flash attention: 2-wave blocks, 4 blocks/CU --------------
// R6: the grid (512 blocks) capped occupancy at 2 blocks/CU -- the HW would
// fit 4 (LDS 37 KB, VGPR 112). Same per-wave structure as R2 (64 q/wave,
// whole-tile frag reads, MFMA row-sum, in-register P), but blocks are now
// 2 waves x 64 q = 128 q, grid (64,16) = 1024 blocks = 4/CU: doubled
// inter-block TLP hides the ds_read->write->compute->barrier convoy
// (m114 regime). Staging: 64 threads per tile, one full 128-B row each.
// setprio REVERTED (R5: -5 us; lockstep structure => m190 regime, not m191).
__global__ __launch_bounds__(128, 3) void flash_kernel(
    const bf16* __restrict__ Qp, const bf16* __restrict__ Kp, const bf16* __restrict__ Vt,
    bf16* __restrict__ O) {
    int nh = blockIdx.x, qt = blockIdx.y;   // bid%8 = nh%8 -> head pinned to XCD
    int n = nh >> 4, h = nh & 15;
    int t = threadIdx.x, lane = t & 63, wq = t >> 6;
    int m = lane & 15, q8 = lane >> 4;
    __shared__ __align__(16) bf16 sK[2 * 64 * LDSP];
    __shared__ __align__(16) bf16 sV[2 * 64 * LDSP];
    size_t nhs = (size_t)nh;
    int qb = qt * 128 + wq * 64;
    const bf16* Qb = Qp + (nhs * SEQ + qb) * HD;
    const bf16* Kb = Kp + nhs * SEQ * HD;
    const bf16* Vb = Vt + nhs * (size_t)HD * SEQ;

    // staging map: threads 0..63 -> K tile, 64..127 -> V tile; one row each
    bool isK = t < 64;
    int srow = t & 63;
    const bf16* sbase = isK ? (Kb + (size_t)srow * HD) : (Vb + (size_t)srow * SEQ);
    size_t sstride = isK ? (size_t)HD : 1;  // advance per k-index
    bf16* ldst0 = (isK ? sK : sV) + srow * LDSP;

    bf16x8 qf[4][2];
    for (int ntq = 0; ntq < 4; ntq++)
        for (int c = 0; c < 2; c++)
            qf[ntq][c] = *(const bf16x8*)(Qb + (ntq * 16 + m) * HD + c * 32 + q8 * 8);

    bf16x8 ones;
    for (int i = 0; i < 8; i++) ones[i] = (bf16)1.0f;

    f32x4 z = {0.f, 0.f, 0.f, 0.f};
    f32x4 accO[4][4];
    for (int a = 0; a < 4; a++)
        for (int b = 0; b < 4; b++) accO[a][b] = z;
    f32x4 accL[4] = {z, z, z, z};

    bf16x8 stg[8];
    auto load_stage = [&](int kb) {
#pragma unroll
        for (int j = 0; j < 8; j++)
            stg[j] = *(const bf16x8*)(sbase + (size_t)kb * sstride + j * 8);
    };
    auto write_stage = [&](int p) {
        bf16* d = ldst0 + p * (64 * LDSP);
#pragma unroll
        for (int j = 0; j < 8; j++)
            *(bf16x8*)(d + j * 8) = stg[j];
    };

    load_stage(0);
    write_stage(0);
    __syncthreads();
    load_stage(64);   // tile 1 -> regs

    int p = 0;
    for (int kb = 0; kb < SEQ; kb += 64) {
        // frag reads of tile kb from buf p
        const bf16* kB = sK + p * (64 * LDSP);
        const bf16* vB = sV + p * (64 * LDSP);
        bf16x8 kf[4][2];
#pragma unroll
        for (int kt = 0; kt < 4; kt++)
#pragma unroll
            for (int c = 0; c < 2; c++)
                kf[kt][c] = *(const bf16x8*)&kB[(kt * 16 + m) * LDSP + c * 32 + q8 * 8];
        bf16x8 vf[4][2];
#pragma unroll
        for (int dt = 0; dt < 4; dt++)
#pragma unroll
            for (int c = 0; c < 2; c++)
                vf[dt][c] = *(const bf16x8*)&vB[(dt * 16 + m) * LDSP + c * 32 + q8 * 8];
        write_stage(p ^ 1);                    // install tile kb+64 into other buf
        load_stage((kb + 128) & (SEQ - 1));    // tile kb+2 -> regs (full body to land)

        // compute on tile kb, one 16-q group at a time (bounds st register life)
#pragma unroll
        for (int ntq = 0; ntq < 4; ntq++) {
            f32x4 st[4];
#pragma unroll
            for (int kt = 0; kt < 4; kt++) st[kt] = z;
#pragma unroll
            for (int c = 0; c < 2; c++)
#pragma unroll
                for (int kt = 0; kt < 4; kt++)
                    st[kt] = MFMA16(kf[kt][c], qf[ntq][c], st[kt]);
            // p = exp2(s); C-layout -> A-frag layout via permlane swaps
            f32x4 pr[4];
#pragma unroll
            for (int kt = 0; kt < 4; kt++) {
                pr[kt][0] = EXP2(st[kt][0]);
                pr[kt][1] = EXP2(st[kt][1]);
                pr[kt][2] = EXP2(st[kt][2]);
                pr[kt][3] = EXP2(st[kt][3]);
            }
            bf16x8 pf[2];
#pragma unroll
            for (int c = 0; c < 2; c++) {
                unsigned dw[4];
#pragma unroll
                for (int i = 0; i < 2; i++) {
                    unsigned u = pack2(pr[2 * c][2 * i], pr[2 * c][2 * i + 1]);
                    unsigned v = pack2(pr[2 * c + 1][2 * i], pr[2 * c + 1][2 * i + 1]);
                    SWAP32(u, v);
                    SWAP16(u, v);
                    dw[i] = u;
                    dw[2 + i] = v;
                }
                union { unsigned u[4]; bf16x8 v; } cvt;
                cvt.u[0] = dw[0]; cvt.u[1] = dw[1];
                cvt.u[2] = dw[2]; cvt.u[3] = dw[3];
                pf[c] = cvt.v;
            }
            // O += P V ; l += P * 1 (row-sum on the MFMA pipe)
#pragma unroll
            for (int c = 0; c < 2; c++) {
#pragma unroll
                for (int dt = 0; dt < 4; dt++)
                    accO[ntq][dt] = MFMA16(pf[c], vf[dt][c], accO[ntq][dt]);
                accL[ntq] = MFMA16(pf[c], ones, accL[ntq]);
            }
        }
        __syncthreads();   // buf p reads done; buf p^1 writes visible
        p ^= 1;
    }

    for (int mtq = 0; mtq < 4; mtq++)
        for (int j = 0; j < 4; j++) {
            float iv = 1.0f / accL[mtq][j];
            int q = qb + mtq * 16 + q8 * 4 + j;
            size_t ro = ((size_t)n * SEQ + q) * EMBED + h * HD;
            for (int dt = 0; dt < 4; dt++)
                O[ro + dt * 16 + m] = (bf16)(accO[mtq][dt][j] * iv);
        }
}

// ---------------- output projection: double-buffered 128x128 GEMM ----------
// (R4 structure, unchanged this round.)
__global__ __launch_bounds__(256, 2) void outproj_kernel(
    const bf16* __restrict__ O, const bf16* __restrict__ Wob,
    const float* __restrict__ bo, float* __restrict__ out) {
    __shared__ __align__(16) bf16 sA[2 * 128 * LDSP];
    __shared__ __align__(16) bf16 sB[2 * 128 * LDSP];
    int bid = blockIdx.x;
    int xcd = bid & 7, idx = bid >> 3;
    int qt = xcd * 8 + (idx & 7), et = idx >> 3;
    int t = threadIdx.x, lane = t & 63, wq = t >> 6;
    int m = lane & 15, q8 = lane >> 4;
    int wr = wq >> 1, wc = wq & 1;
    int qb = qt * 128, cb = et * 128;

    // staging: threads 0..127 -> A rows (O), 128..255 -> B rows (Wob)
    bool isA = t < 128;
    int r = t & 127;
    const bf16* sbase = isA ? (O + (size_t)(qb + r) * EMBED)
                            : (Wob + (size_t)(cb + r) * EMBED);
    bf16* ldst0 = (isA ? sA : sB) + r * LDSP;

    bf16x8 stg[8];
    auto load_stage = [&](int kk) {
#pragma unroll
        for (int j = 0; j < 8; j++)
            stg[j] = *(const bf16x8*)(sbase + kk + j * 8);
    };
    auto write_stage = [&](int p) {
        bf16* d = ldst0 + p * (128 * LDSP);
#pragma unroll
        for (int j = 0; j < 8; j++)
            *(bf16x8*)(d + j * 8) = stg[j];
    };

    f32x4 z = {0.f, 0.f, 0.f, 0.f};
    f32x4 acc[4][4];
    for (int a = 0; a < 4; a++)
        for (int b = 0; b < 4; b++) acc[a][b] = z;

    load_stage(0);
    write_stage(0);
    __syncthreads();
    load_stage(64);   // tile 1 -> regs

    int p = 0;
    for (int kk = 0; kk < EMBED; kk += 64) {
        const bf16* aB = sA + p * (128 * LDSP);
        const bf16* bB = sB + p * (128 * LDSP);
        bf16x8 af[4][2], bfr[4][2];
#pragma unroll
        for (int mt = 0; mt < 4; mt++)
#pragma unroll
            for (int c = 0; c < 2; c++)
                af[mt][c] = *(const bf16x8*)&aB[(wr * 64 + mt * 16 + m) * LDSP + c * 32 + q8 * 8];
#pragma unroll
        for (int nt = 0; nt < 4; nt++)
#pragma unroll
            for (int c = 0; c < 2; c++)
                bfr[nt][c] = *(const bf16x8*)&bB[(wc * 64 + nt * 16 + m) * LDSP + c * 32 + q8 * 8];
        write_stage(p ^ 1);                      // install tile kk+64
        load_stage((kk + 128) & (EMBED - 1));    // tile kk+2 -> regs

#pragma unroll
        for (int c = 0; c < 2; c++)
#pragma unroll
            for (int mt = 0; mt < 4; mt++)
#pragma unroll
                for (int nt = 0; nt < 4; nt++)
                    acc[mt][nt] = MFMA16(af[mt][c], bfr[nt][c], acc[mt][nt]);
        __syncthreads();
        p ^= 1;
    }

    for (int nt = 0; nt < 4; nt++) {
        int col = cb + wc * 64 + nt * 16 + m;
        float bias = bo[col];
        for (int mt = 0; mt < 4; mt++)
            for (int j = 0; j < 4; j++) {
                int q = qb + wr * 64 + mt * 16 + q8 * 4 + j;
                out[(size_t)q * EMBED + col] = acc[mt][nt][j] + bias;
            }
    }
}

extern "C" void kernel_launch(void* const* d_in, const int* in_sizes, int n_in,
                              void* d_out, int out_size, void* d_ws, size_t ws_size,
                              hipStream_t stream) {
    const float* values = (const float*)d_in[0];
    const float* keys   = (const float*)d_in[1];
    const float* query  = (const float*)d_in[2];
    const float* Wv     = (const float*)d_in[3];
    const float* Wk     = (const float*)d_in[4];
    const float* Wq     = (const float*)d_in[5];
    const float* Wo     = (const float*)d_in[6];
    const float* bo     = (const float*)d_in[7];
    float* out = (float*)d_out;

    char* ws = (char*)d_ws;
    bf16* Qp  = (bf16*)(ws);
    bf16* Kp  = (bf16*)(ws + (size_t)(16 << 20));
    bf16* Vt  = (bf16*)(ws + (size_t)(32 << 20));
    bf16* O   = (bf16*)(ws + (size_t)(48 << 20));
    bf16* Wob = (bf16*)(ws + (size_t)(64 << 20));
    bf16* Wqb = (bf16*)(ws + (size_t)(66 << 20));
    bf16* Wkb = (bf16*)(ws + (size_t)(66 << 20) + 8192);
    bf16* Wvb = (bf16*)(ws + (size_t)(66 << 20) + 16384);

    hipLaunchKernelGGL(convert_weights, dim3(518), dim3(256), 0, stream,
                       Wo, Wq, Wk, Wv, Wob, Wqb, Wkb, Wvb);
    hipLaunchKernelGGL(proj_kernel, dim3(2048), dim3(256), 0, stream,
                       values, keys, query, Wqb, Wkb, Wvb, Vt, Kp, Qp);
    hipLaunchKernelGGL(flash_kernel, dim3(64, 16), dim3(128), 0, stream, Qp, Kp, Vt, O);
    hipLaunchKernelGGL(outproj_kernel, dim3(512), dim3(256), 0, stream, O, Wob, bo, out);
}

// Round 8
// 273.280 us; speedup vs baseline: 1.1323x; 1.1323x over previous
//
#include <hip/hip_runtime.h>
#include <hip/hip_bf16.h>

typedef __bf16 bf16;
typedef __bf16 bf16x2 __attribute__((ext_vector_type(2)));
typedef __bf16 bf16x4 __attribute__((ext_vector_type(4)));
typedef __bf16 bf16x8 __attribute__((ext_vector_type(8)));
typedef float f32x4 __attribute__((ext_vector_type(4)));

#define MFMA16(a, b, c) __builtin_amdgcn_mfma_f32_16x16x32_bf16((a), (b), (c), 0, 0, 0)

#if __has_builtin(__builtin_amdgcn_exp2f)
#define EXP2(x) __builtin_amdgcn_exp2f(x)
#else
#define EXP2(x) exp2f(x)
#endif

constexpr int EMBED = 1024;
constexpr int HEADS = 16;
constexpr int HD = 64;
constexpr int SEQ = 2048;
constexpr int LDSP = 72;   // padded LDS stride: 144 B rows (16B-aligned, 2-way banks = free)
constexpr int SXTP = 76;   // proj V-transpose stride
constexpr int WO_N = EMBED * EMBED;

// softmax scale 1/sqrt(1024) folded with log2(e); folded into Wq conversion
#define QSCALE 0.04508422082f

// pack two f32 -> one dword of 2 bf16 (compiler emits v_cvt_pk_bf16_f32)
static __device__ __forceinline__ unsigned pack2(float a, float b) {
    bf16x2 t;
    t[0] = (bf16)a;
    t[1] = (bf16)b;
    return __builtin_bit_cast(unsigned, t);
}
// gfx950 in-register half/row swaps (both operands read+write)
#define SWAP32(x, y) asm("v_permlane32_swap_b32 %0, %1" : "+v"(x), "+v"(y))
#define SWAP16(x, y) asm("v_permlane16_swap_b32 %0, %1" : "+v"(x), "+v"(y))

// ---------------- all weights fp32 -> bf16 (Q scale folded into Wq) --------
__global__ __launch_bounds__(256) void convert_weights(
    const float* __restrict__ Wo, const float* __restrict__ Wq,
    const float* __restrict__ Wk, const float* __restrict__ Wv,
    bf16* __restrict__ Wob, bf16* __restrict__ Wqb,
    bf16* __restrict__ Wkb, bf16* __restrict__ Wvb) {
    int gid = blockIdx.x * 256 + threadIdx.x;
    int base = gid * 8;
    const float* src;
    bf16* dst;
    float sc = 1.0f;
    int off;
    if (base < WO_N) {
        src = Wo; dst = Wob; off = base;
    } else {
        int j = base - WO_N;
        int w = j >> 12;
        off = j & 4095;
        src = (w == 0) ? Wq : (w == 1) ? Wk : Wv;
        dst = (w == 0) ? Wqb : (w == 1) ? Wkb : Wvb;
        if (w == 0) sc = QSCALE;
    }
    float4 a = *(const float4*)(src + off);
    float4 b = *(const float4*)(src + off + 4);
    bf16x8 o;
    o[0] = (bf16)(a.x * sc); o[1] = (bf16)(a.y * sc);
    o[2] = (bf16)(a.z * sc); o[3] = (bf16)(a.w * sc);
    o[4] = (bf16)(b.x * sc); o[5] = (bf16)(b.y * sc);
    o[6] = (bf16)(b.z * sc); o[7] = (bf16)(b.w * sc);
    *(bf16x8*)(dst + off) = o;
}

// ---------------- QKV per-head projections ----------------
// R7: XCD-grouped grid swizzle. A block covers only 4 consecutive l, so each
// 64 B line of Vt (32 l) is written by 8 consecutive bids; unswizzled these
// round-robin across 8 XCDs -> 8 non-coherent L2s each evict a partial
// dirty line (masked HBM writes, ~8x V-write amplification). Swizzle
// bid = (g&7)*256 + (g>>3): the 8 line-sharing blocks land on ONE XCD, the
// partial writes merge in its L2, lines evict once. Also gives each XCD a
// contiguous (n,l) input slab.
__global__ __launch_bounds__(256) void proj_kernel(
    const float* __restrict__ Vx, const float* __restrict__ Kx, const float* __restrict__ Qx,
    const bf16* __restrict__ Wqb, const bf16* __restrict__ Wkb, const bf16* __restrict__ Wvb,
    bf16* __restrict__ Vt, bf16* __restrict__ Kp, bf16* __restrict__ Qp) {
    __shared__ __align__(16) bf16 sT0[64 * LDSP];
    __shared__ __align__(16) bf16 sT1[64 * LDSP];
    __shared__ __align__(16) bf16 sXT[64 * SXTP];
    int g = blockIdx.x;
    int bid = (g & 7) * 256 + (g >> 3);   // bijective: 8 consecutive bids -> same XCD
    int t = threadIdx.x, lane = t & 63, wq = t >> 6;
    int m = lane & 15, q8 = lane >> 4;
    int rowbase = bid * 64;
    int Arow = rowbase + wq * 16 + m;
    const float* Xs[3] = {Qx, Kx, Vx};
    const bf16* Ws[3] = {Wqb, Wkb, Wvb};
    f32x4 z = {0.f, 0.f, 0.f, 0.f};

    // hoisted A loads (T14 issue-early): all 3 ts stages' rows at once
    float4 ax[3][2][2];
#pragma unroll
    for (int ts = 0; ts < 3; ts++)
#pragma unroll
        for (int c = 0; c < 2; c++) {
            const float* s = Xs[ts] + (size_t)Arow * 64 + c * 32 + q8 * 8;
            ax[ts][c][0] = *(const float4*)s;
            ax[ts][c][1] = *(const float4*)(s + 4);
        }

#pragma unroll
    for (int ts = 0; ts < 3; ts++) {
        bf16x8 af[2];
#pragma unroll
        for (int c = 0; c < 2; c++) {
            float4 x0 = ax[ts][c][0];
            float4 x1 = ax[ts][c][1];
            bf16x8 a;
            a[0] = (bf16)x0.x; a[1] = (bf16)x0.y; a[2] = (bf16)x0.z; a[3] = (bf16)x0.w;
            a[4] = (bf16)x1.x; a[5] = (bf16)x1.y; a[6] = (bf16)x1.z; a[7] = (bf16)x1.w;
            af[c] = a;
        }
        bf16x8 bfr[4][2];
#pragma unroll
        for (int nt = 0; nt < 4; nt++)
#pragma unroll
            for (int c = 0; c < 2; c++)
                bfr[nt][c] = *(const bf16x8*)(Ws[ts] + (nt * 16 + m) * 64 + c * 32 + q8 * 8);
        f32x4 acc[4] = {z, z, z, z};
#pragma unroll
        for (int c = 0; c < 2; c++)
#pragma unroll
            for (int nt = 0; nt < 4; nt++)
                acc[nt] = MFMA16(af[c], bfr[nt][c], acc[nt]);

        if (ts < 2) {
            bf16* sT = (ts == 0) ? sT0 : sT1;   // static per unrolled ts
            for (int nt = 0; nt < 4; nt++)
                for (int jr = 0; jr < 4; jr++)
                    sT[(wq * 16 + q8 * 4 + jr) * LDSP + nt * 16 + m] = (bf16)acc[nt][jr];
            __syncthreads();
            // coalesced store: 4 threads per row, 16B chunks
            int r = t >> 2, c4 = t & 3;
            int R = rowbase + r;
            int h = R & 15, l = (R >> 4) & 2047, n = R >> 15;
            bf16* dst = ((ts == 0) ? Qp : Kp) + ((size_t)(n * HEADS + h) * SEQ + l) * HD + c4 * 16;
            bf16x8 v0 = *(const bf16x8*)&sT[r * LDSP + c4 * 16];
            bf16x8 v1 = *(const bf16x8*)&sT[r * LDSP + c4 * 16 + 8];
            *(bf16x8*)dst = v0;
            *(bf16x8*)(dst + 8) = v1;
        } else {
            // V: acc -> sXT[e][r], gather-transpose to Vt[n,h,d,l] (b64 stores)
            for (int nt = 0; nt < 4; nt++) {
                bf16x4 pv;
                pv[0] = (bf16)acc[nt][0]; pv[1] = (bf16)acc[nt][1];
                pv[2] = (bf16)acc[nt][2]; pv[3] = (bf16)acc[nt][3];
                *(bf16x4*)&sXT[(nt * 16 + m) * SXTP + wq * 16 + q8 * 4] = pv;
            }
            __syncthreads();
            int n = rowbase >> 15, l0 = (rowbase >> 4) & 2047;
            for (int i = t; i < 1024; i += 256) {
                int e = i & 63, hh = i >> 6;
                bf16x4 pv;
                pv[0] = sXT[e * SXTP + 0 * 16 + hh];
                pv[1] = sXT[e * SXTP + 1 * 16 + hh];
                pv[2] = sXT[e * SXTP + 2 * 16 + hh];
                pv[3] = sXT[e * SXTP + 3 * 16 + hh];
                *(bf16x4*)(Vt + ((size_t)(n * HEADS + hh) * HD + e) * SEQ + l0) = pv;
            }
        }
    }
}

// ---------------- flash attention: double-buffered LDS, 1 barrier/iter ----
// R7: exact revert to the R4 structure (best measured: 76.0 us). 256
// threads, 4 waves x 64 q, MFMA row-sum, in-register P, no setprio
// (R5: -5 us), no 2-wave blocks (R6: occupancy collapsed, +27 us).
__global__ __launch_bounds__(256, 2) void flash_kernel(
    const bf16* __restrict__ Qp, const bf16* __restrict__ Kp, const bf16* __restrict__ Vt,
    bf16* __restrict__ O) {
    int nh = blockIdx.x, qt = blockIdx.y;   // all qt of one head -> same XCD
    int n = nh >> 4, h = nh & 15;
    int t = threadIdx.x, lane = t & 63, wq = t >> 6;
    int m = lane & 15, q8 = lane >> 4;
    __shared__ __align__(16) bf16 sK[2 * 64 * LDSP];
    __shared__ __align__(16) bf16 sV[2 * 64 * LDSP];
    size_t nhs = (size_t)nh;
    int qb = qt * 256 + wq * 64;
    const bf16* Qb = Qp + (nhs * SEQ + qb) * HD;
    const bf16* Kb = Kp + nhs * SEQ * HD;
    const bf16* Vb = Vt + nhs * (size_t)HD * SEQ;

    // staging map: threads 0..127 -> K tile (row, half-row), 128..255 -> V tile
    bool isK = t < 128;
    int t2 = isK ? t : t - 128;
    int srow = t2 >> 1, shalf = t2 & 1;
    const bf16* sbase = isK ? (Kb + (size_t)srow * HD + shalf * 32)
                            : (Vb + (size_t)srow * SEQ + shalf * 32);
    size_t sstride = isK ? (size_t)HD : 1;  // advance per k-index
    bf16* ldst0 = (isK ? sK : sV) + srow * LDSP + shalf * 32;

    bf16x8 qf[4][2];
    for (int ntq = 0; ntq < 4; ntq++)
        for (int c = 0; c < 2; c++)
            qf[ntq][c] = *(const bf16x8*)(Qb + (ntq * 16 + m) * HD + c * 32 + q8 * 8);

    bf16x8 ones;
    for (int i = 0; i < 8; i++) ones[i] = (bf16)1.0f;

    f32x4 z = {0.f, 0.f, 0.f, 0.f};
    f32x4 accO[4][4];
    for (int a = 0; a < 4; a++)
        for (int b = 0; b < 4; b++) accO[a][b] = z;
    f32x4 accL[4] = {z, z, z, z};

    bf16x8 stg[4];
    auto load_stage = [&](int kb) {
#pragma unroll
        for (int j = 0; j < 4; j++)
            stg[j] = *(const bf16x8*)(sbase + (size_t)kb * sstride + j * 8);
    };
    auto write_stage = [&](int p) {
        bf16* d = ldst0 + p * (64 * LDSP);
#pragma unroll
        for (int j = 0; j < 4; j++)
            *(bf16x8*)(d + j * 8) = stg[j];
    };

    load_stage(0);
    write_stage(0);
    __syncthreads();
    load_stage(64);   // tile 1 -> regs

    int p = 0;
    for (int kb = 0; kb < SEQ; kb += 64) {
        // frag reads of tile kb from buf p
        const bf16* kB = sK + p * (64 * LDSP);
        const bf16* vB = sV + p * (64 * LDSP);
        bf16x8 kf[4][2];
#pragma unroll
        for (int kt = 0; kt < 4; kt++)
#pragma unroll
            for (int c = 0; c < 2; c++)
                kf[kt][c] = *(const bf16x8*)&kB[(kt * 16 + m) * LDSP + c * 32 + q8 * 8];
        bf16x8 vf[4][2];
#pragma unroll
        for (int dt = 0; dt < 4; dt++)
#pragma unroll
            for (int c = 0; c < 2; c++)
                vf[dt][c] = *(const bf16x8*)&vB[(dt * 16 + m) * LDSP + c * 32 + q8 * 8];
        write_stage(p ^ 1);                    // install tile kb+64 into other buf
        load_stage((kb + 128) & (SEQ - 1));    // tile kb+2 -> regs (full body to land)

        // compute on tile kb, one 16-q group at a time (bounds st register life)
#pragma unroll
        for (int ntq = 0; ntq < 4; ntq++) {
            f32x4 st[4];
#pragma unroll
            for (int kt = 0; kt < 4; kt++) st[kt] = z;
#pragma unroll
            for (int c = 0; c < 2; c++)
#pragma unroll
                for (int kt = 0; kt < 4; kt++)
                    st[kt] = MFMA16(kf[kt][c], qf[ntq][c], st[kt]);
            // p = exp2(s); C-layout -> A-frag layout via permlane swaps
            f32x4 pr[4];
#pragma unroll
            for (int kt = 0; kt < 4; kt++) {
                pr[kt][0] = EXP2(st[kt][0]);
                pr[kt][1] = EXP2(st[kt][1]);
                pr[kt][2] = EXP2(st[kt][2]);
                pr[kt][3] = EXP2(st[kt][3]);
            }
            bf16x8 pf[2];
#pragma unroll
            for (int c = 0; c < 2; c++) {
                unsigned dw[4];
#pragma unroll
                for (int i = 0; i < 2; i++) {
                    unsigned u = pack2(pr[2 * c][2 * i], pr[2 * c][2 * i + 1]);
                    unsigned v = pack2(pr[2 * c + 1][2 * i], pr[2 * c + 1][2 * i + 1]);
                    SWAP32(u, v);
                    SWAP16(u, v);
                    dw[i] = u;
                    dw[2 + i] = v;
                }
                union { unsigned u[4]; bf16x8 v; } cvt;
                cvt.u[0] = dw[0]; cvt.u[1] = dw[1];
                cvt.u[2] = dw[2]; cvt.u[3] = dw[3];
                pf[c] = cvt.v;
            }
            // O += P V ; l += P * 1 (row-sum on the MFMA pipe)
#pragma unroll
            for (int c = 0; c < 2; c++) {
#pragma unroll
                for (int dt = 0; dt < 4; dt++)
                    accO[ntq][dt] = MFMA16(pf[c], vf[dt][c], accO[ntq][dt]);
                accL[ntq] = MFMA16(pf[c], ones, accL[ntq]);
            }
        }
        __syncthreads();   // buf p reads done; buf p^1 writes visible
        p ^= 1;
    }

    for (int mtq = 0; mtq < 4; mtq++)
        for (int j = 0; j < 4; j++) {
            float iv = 1.0f / accL[mtq][j];
            int q = qb + mtq * 16 + q8 * 4 + j;
            size_t ro = ((size_t)n * SEQ + q) * EMBED + h * HD;
            for (int dt = 0; dt < 4; dt++)
                O[ro + dt * 16 + m] = (bf16)(accO[mtq][dt][j] * iv);
        }
}

// ---------------- output projection: double-buffered 128x128 GEMM ----------
// (R4 structure, unchanged this round.)
__global__ __launch_bounds__(256, 2) void outproj_kernel(
    const bf16* __restrict__ O, const bf16* __restrict__ Wob,
    const float* __restrict__ bo, float* __restrict__ out) {
    __shared__ __align__(16) bf16 sA[2 * 128 * LDSP];
    __shared__ __align__(16) bf16 sB[2 * 128 * LDSP];
    int bid = blockIdx.x;
    int xcd = bid & 7, idx = bid >> 3;
    int qt = xcd * 8 + (idx & 7), et = idx >> 3;
    int t = threadIdx.x, lane = t & 63, wq = t >> 6;
    int m = lane & 15, q8 = lane >> 4;
    int wr = wq >> 1, wc = wq & 1;
    int qb = qt * 128, cb = et * 128;

    // staging: threads 0..127 -> A rows (O), 128..255 -> B rows (Wob)
    bool isA = t < 128;
    int r = t & 127;
    const bf16* sbase = isA ? (O + (size_t)(qb + r) * EMBED)
                            : (Wob + (size_t)(cb + r) * EMBED);
    bf16* ldst0 = (isA ? sA : sB) + r * LDSP;

    bf16x8 stg[8];
    auto load_stage = [&](int kk) {
#pragma unroll
        for (int j = 0; j < 8; j++)
            stg[j] = *(const bf16x8*)(sbase + kk + j * 8);
    };
    auto write_stage = [&](int p) {
        bf16* d = ldst0 + p * (128 * LDSP);
#pragma unroll
        for (int j = 0; j < 8; j++)
            *(bf16x8*)(d + j * 8) = stg[j];
    };

    f32x4 z = {0.f, 0.f, 0.f, 0.f};
    f32x4 acc[4][4];
    for (int a = 0; a < 4; a++)
        for (int b = 0; b < 4; b++) acc[a][b] = z;

    load_stage(0);
    write_stage(0);
    __syncthreads();
    load_stage(64);   // tile 1 -> regs

    int p = 0;
    for (int kk = 0; kk < EMBED; kk += 64) {
        const bf16* aB = sA + p * (128 * LDSP);
        const bf16* bB = sB + p * (128 * LDSP);
        bf16x8 af[4][2], bfr[4][2];
#pragma unroll
        for (int mt = 0; mt < 4; mt++)
#pragma unroll
            for (int c = 0; c < 2; c++)
                af[mt][c] = *(const bf16x8*)&aB[(wr * 64 + mt * 16 + m) * LDSP + c * 32 + q8 * 8];
#pragma unroll
        for (int nt = 0; nt < 4; nt++)
#pragma unroll
            for (int c = 0; c < 2; c++)
                bfr[nt][c] = *(const bf16x8*)&bB[(wc * 64 + nt * 16 + m) * LDSP + c * 32 + q8 * 8];
        write_stage(p ^ 1);                      // install tile kk+64
        load_stage((kk + 128) & (EMBED - 1));    // tile kk+2 -> regs

#pragma unroll
        for (int c = 0; c < 2; c++)
#pragma unroll
            for (int mt = 0; mt < 4; mt++)
#pragma unroll
                for (int nt = 0; nt < 4; nt++)
                    acc[mt][nt] = MFMA16(af[mt][c], bfr[nt][c], acc[mt][nt]);
        __syncthreads();
        p ^= 1;
    }

    for (int nt = 0; nt < 4; nt++) {
        int col = cb + wc * 64 + nt * 16 + m;
        float bias = bo[col];
        for (int mt = 0; mt < 4; mt++)
            for (int j = 0; j < 4; j++) {
                int q = qb + wr * 64 + mt * 16 + q8 * 4 + j;
                out[(size_t)q * EMBED + col] = acc[mt][nt][j] + bias;
            }
    }
}

extern "C" void kernel_launch(void* const* d_in, const int* in_sizes, int n_in,
                              void* d_out, int out_size, void* d_ws, size_t ws_size,
                              hipStream_t stream) {
    const float* values = (const float*)d_in[0];
    const float* keys   = (const float*)d_in[1];
    const float* query  = (const float*)d_in[2];
    const float* Wv     = (const float*)d_in[3];
    const float* Wk     = (const float*)d_in[4];
    const float* Wq     = (const float*)d_in[5];
    const float* Wo     = (const float*)d_in[6];
    const float* bo     = (const float*)d_in[7];
    float* out = (float*)d_out;

    char* ws = (char*)d_ws;
    bf16* Qp  = (bf16*)(ws);
    bf16* Kp  = (bf16*)(ws + (size_t)(16 << 20));
    bf16* Vt  = (bf16*)(ws + (size_t)(32 << 20));
    bf16* O   = (bf16*)(ws + (size_t)(48 << 20));
    bf16* Wob = (bf16*)(ws + (size_t)(64 << 20));
    bf16* Wqb = (bf16*)(ws + (size_t)(66 << 20));
    bf16* Wkb = (bf16*)(ws + (size_t)(66 << 20) + 8192);
    bf16* Wvb = (bf16*)(ws + (size_t)(66 << 20) + 16384);

    hipLaunchKernelGGL(convert_weights, dim3(518), dim3(256), 0, stream,
                       Wo, Wq, Wk, Wv, Wob, Wqb, Wkb, Wvb);
    hipLaunchKernelGGL(proj_kernel, dim3(2048), dim3(256), 0, stream,
                       values, keys, query, Wqb, Wkb, Wvb, Vt, Kp, Qp);
    hipLaunchKernelGGL(flash_kernel, dim3(64, 8), dim3(256), 0, stream, Qp, Kp, Vt, O);
    hipLaunchKernelGGL(outproj_kernel, dim3(512), dim3(256), 0, stream, O, Wob, bo, out);
}